// Round 12
// baseline (1157.302 us; speedup 1.0000x reference)
//
#include <hip/hip_runtime.h>
#include <hip/hip_fp16.h>

#define NUM_STEPS 5
typedef unsigned int u32;
typedef unsigned long long ull;

// ---------------- fast path constants ----------------
#define RSH 10             // 1024 nodes per dst-bucket
#define RSZ 1024
#define SB  1024           // hist/scatter blocks (chunking MUST match between them)
#define HT  512            // hist threads
#define ST  512            // scatter threads
#define NBMAX 512          // max buckets supported by scatter LDS bins
#define BINS 8             // scatter bin slots (8 x 8B = 64B line)
#define SPLIT 4            // step blocks per bucket
#define SRC_BITS 19        // N=500000 < 2^19
#define SRC_MASK 0x7FFFFu

static inline size_t align256(size_t x){ return (x + 255) & ~(size_t)255; }

// ---------------- fast-path kernels ----------------

__global__ void init_fast(const float* __restrict__ prior, __half* __restrict__ p,
                          float* __restrict__ prod, int n){
    int i = blockIdx.x*blockDim.x + threadIdx.x;
    if(i<n){ p[i]=__float2half_rn(prior[i]); prod[i]=1.0f; }
}

// per-block histogram of edge targets into B buckets (int4-vectorized)
__global__ void hist_kernel(const int* __restrict__ dst, long long E, int B,
                            u32* __restrict__ blk_cnt){
    extern __shared__ u32 hist[];
    int sb = blockIdx.x;
    long long E4 = E >> 2;
    long long chunk = (E4 + SB - 1)/SB;
    long long i0 = (long long)sb*chunk;
    long long i1 = i0 + chunk; if(i1 > E4) i1 = E4;
    for(int b=threadIdx.x; b<B; b+=blockDim.x) hist[b]=0;
    __syncthreads();
    const int4* d4 = (const int4*)dst;
    for(long long i=i0+threadIdx.x; i<i1; i+=blockDim.x){
        int4 d = d4[i];
        atomicAdd(&hist[((u32)d.x)>>RSH], 1u);
        atomicAdd(&hist[((u32)d.y)>>RSH], 1u);
        atomicAdd(&hist[((u32)d.z)>>RSH], 1u);
        atomicAdd(&hist[((u32)d.w)>>RSH], 1u);
    }
    if(sb==0){   // scalar tail (E % 4)
        for(long long e=(E4<<2)+threadIdx.x; e<E; e+=blockDim.x)
            atomicAdd(&hist[((u32)dst[e])>>RSH], 1u);
    }
    __syncthreads();
    for(int b=threadIdx.x; b<B; b+=blockDim.x) blk_cnt[(size_t)sb*B + b] = hist[b];
}

// per-bucket exclusive scan over the SB per-block counts (one block per bucket)
__global__ __launch_bounds__(SB) void
colscan_kernel(u32* __restrict__ blk_cnt, int B, u32* __restrict__ tot){
    __shared__ u32 s[SB];
    int b = blockIdx.x, t = threadIdx.x;   // blockDim.x == SB
    u32 v = blk_cnt[(size_t)t*B + b];
    s[t] = v; __syncthreads();
    for(int off=1; off<SB; off<<=1){
        u32 x = (t>=off) ? s[t-off] : 0;
        __syncthreads();
        s[t] += x;
        __syncthreads();
    }
    blk_cnt[(size_t)t*B + b] = s[t] - v;     // exclusive
    if(t==SB-1) tot[b] = s[SB-1];
}

// exclusive scan of bucket totals -> bucket base offsets (single block, B <= 512)
__global__ void basescan_kernel(const u32* __restrict__ tot, u32* __restrict__ base, int B){
    __shared__ u32 s[256];
    int t = threadIdx.x;
    u32 v0 = (2*t   < B) ? tot[2*t]   : 0;
    u32 v1 = (2*t+1 < B) ? tot[2*t+1] : 0;
    u32 sum = v0 + v1;
    s[t] = sum; __syncthreads();
    for(int off=1; off<256; off<<=1){
        u32 x = (t>=off) ? s[t-off] : 0;
        __syncthreads();
        s[t] += x;
        __syncthreads();
    }
    u32 run = s[t] - sum;
    if(2*t   < B) base[2*t]   = run;
    if(2*t+1 < B) base[2*t+1] = run + v0;
    if(t==255) base[B] = s[255];     // == E
}

// LDS-binned scatter: proven round-5 flush protocol, SB=1024 for occupancy
__global__ __launch_bounds__(ST) void
scatter_kernel(const int* __restrict__ src, const int* __restrict__ dst,
               const float* __restrict__ ep, long long E, int B,
               const u32* __restrict__ blk_rel, const u32* __restrict__ base,
               uint2* __restrict__ edges){
    __shared__ uint2 bin[NBMAX][BINS];   // 32 KB
    __shared__ u32 cnt[NBMAX];
    __shared__ u32 gcur[NBMAX];
    const int sb = blockIdx.x, t = threadIdx.x;
    long long E4 = E >> 2;
    long long chunk = (E4 + SB - 1)/SB;
    long long i0 = (long long)sb*chunk;
    long long i1 = i0 + chunk; if(i1 > E4) i1 = E4;
    for(int b=t; b<B; b+=ST){ cnt[b]=0; gcur[b]=base[b]+blk_rel[(size_t)sb*B+b]; }
    __syncthreads();
    const int4*   s4=(const int4*)src;
    const int4*   d4=(const int4*)dst;
    const float4* w4=(const float4*)ep;
    for(long long it=i0; it<i1; it+=ST){
        long long i = it + t;
        bool valid = (i < i1);
        u32 bk[4]; u32 sl[4]; uint2 pl[4];
        if(valid){
            int4 s=s4[i]; int4 d=d4[i]; float4 w=w4[i];
            u32 dd;
            dd=(u32)d.x; bk[0]=dd>>RSH; pl[0]=make_uint2(((u32)s.x)|((dd&(RSZ-1))<<SRC_BITS), __float_as_uint(w.x));
            dd=(u32)d.y; bk[1]=dd>>RSH; pl[1]=make_uint2(((u32)s.y)|((dd&(RSZ-1))<<SRC_BITS), __float_as_uint(w.y));
            dd=(u32)d.z; bk[2]=dd>>RSH; pl[2]=make_uint2(((u32)s.z)|((dd&(RSZ-1))<<SRC_BITS), __float_as_uint(w.z));
            dd=(u32)d.w; bk[3]=dd>>RSH; pl[3]=make_uint2(((u32)s.w)|((dd&(RSZ-1))<<SRC_BITS), __float_as_uint(w.w));
            #pragma unroll
            for(int k=0;k<4;k++) sl[k]=atomicAdd(&cnt[bk[k]],1u);
        }
        __syncthreads();
        if(valid){
            #pragma unroll
            for(int k=0;k<4;k++){
                if(sl[k] < BINS) bin[bk[k]][sl[k]] = pl[k];
                else             edges[gcur[bk[k]] + sl[k]] = pl[k];
            }
        }
        __syncthreads();
        for(int b=t; b<B; b+=ST){
            u32 c = cnt[b];
            if(c >= BINS){
                u32 g = gcur[b];
                #pragma unroll
                for(int k2=0;k2<BINS;k2++) edges[g+k2] = bin[b][k2];
                gcur[b] = g + c;
                cnt[b]  = 0;
            }
        }
        __syncthreads();
    }
    if(sb==0){   // tail edges (E % 4)
        long long tb = E4<<2;
        int nt = (int)(E - tb);
        if(nt > 0){
            bool v = (t < nt);
            u32 bk0=0, sl0=0; uint2 pl0=make_uint2(0,0);
            if(v){
                u32 dd=(u32)dst[tb+t]; bk0=dd>>RSH;
                pl0=make_uint2(((u32)src[tb+t])|((dd&(RSZ-1))<<SRC_BITS), __float_as_uint(ep[tb+t]));
                sl0=atomicAdd(&cnt[bk0],1u);
            }
            __syncthreads();
            if(v){ if(sl0<BINS) bin[bk0][sl0]=pl0; else edges[gcur[bk0]+sl0]=pl0; }
            __syncthreads();
        }
    }
    for(int b=t; b<B; b+=ST){
        u32 c = cnt[b]; if(c > BINS) c = BINS;
        u32 g = gcur[b];
        for(u32 k2=0;k2<c;k2++) edges[g+k2] = bin[b][k2];
    }
}

// one step, part 1: SPLIT=4 blocks per bucket, 256 threads, 8-deep ILP,
// 2-replica LDS accumulation (round-11 proven).
__global__ __launch_bounds__(256) void
step_kernel(const uint2* __restrict__ edges, const u32* __restrict__ base,
            const __half* __restrict__ p, float* __restrict__ pacc){
    __shared__ float acc[2][RSZ];      // 8 KB
    int blk = blockIdx.x;
    int b   = blk >> 2;                // SPLIT == 4
    int part= blk & 3;
    int t   = threadIdx.x;
    for(int k=t; k<RSZ; k+=256){ acc[0][k]=0.0f; acc[1][k]=0.0f; }
    __syncthreads();
    u32 e0 = base[b], e1 = base[b+1];
    u32 cnt = e1 - e0;
    u32 s0 = e0 + (cnt*(u32)part)/SPLIT;
    u32 s1 = e0 + (cnt*(u32)(part+1))/SPLIT;
    int rep = t & 1;
    u32 n = s1 - s0;
    u32 m = n >> 11;                   // full 2048-edge iterations (8 x 256)
    u32 eb = s0 + t;
    const ull* ed = (const ull*)edges;
    for(u32 it=0; it<m; ++it){
        ull r0 = ed[eb       ];
        ull r1 = ed[eb +  256];
        ull r2 = ed[eb +  512];
        ull r3 = ed[eb +  768];
        ull r4 = ed[eb + 1024];
        ull r5 = ed[eb + 1280];
        ull r6 = ed[eb + 1536];
        ull r7 = ed[eb + 1792];
        u32 x0=(u32)r0, x1=(u32)r1, x2=(u32)r2, x3=(u32)r3;
        u32 x4=(u32)r4, x5=(u32)r5, x6=(u32)r6, x7=(u32)r7;
        float p0 = __half2float(p[x0 & SRC_MASK]);
        float p1 = __half2float(p[x1 & SRC_MASK]);
        float p2 = __half2float(p[x2 & SRC_MASK]);
        float p3 = __half2float(p[x3 & SRC_MASK]);
        float p4 = __half2float(p[x4 & SRC_MASK]);
        float p5 = __half2float(p[x5 & SRC_MASK]);
        float p6 = __half2float(p[x6 & SRC_MASK]);
        float p7 = __half2float(p[x7 & SRC_MASK]);
        atomicAdd(&acc[rep][x0 >> SRC_BITS], __uint_as_float((u32)(r0>>32))*p0);
        atomicAdd(&acc[rep][x1 >> SRC_BITS], __uint_as_float((u32)(r1>>32))*p1);
        atomicAdd(&acc[rep][x2 >> SRC_BITS], __uint_as_float((u32)(r2>>32))*p2);
        atomicAdd(&acc[rep][x3 >> SRC_BITS], __uint_as_float((u32)(r3>>32))*p3);
        atomicAdd(&acc[rep][x4 >> SRC_BITS], __uint_as_float((u32)(r4>>32))*p4);
        atomicAdd(&acc[rep][x5 >> SRC_BITS], __uint_as_float((u32)(r5>>32))*p5);
        atomicAdd(&acc[rep][x6 >> SRC_BITS], __uint_as_float((u32)(r6>>32))*p6);
        atomicAdd(&acc[rep][x7 >> SRC_BITS], __uint_as_float((u32)(r7>>32))*p7);
        eb += 2048;
    }
    for(u32 e=eb; e<s1; e+=256){
        ull r = ed[e];
        u32 x = (u32)r;
        atomicAdd(&acc[rep][x >> SRC_BITS],
                  __uint_as_float((u32)(r>>32))*__half2float(p[x & SRC_MASK]));
    }
    __syncthreads();
    float* dstp = pacc + (size_t)blk * RSZ;
    for(int k=t; k<RSZ; k+=256) dstp[k] = acc[0][k] + acc[1][k];
}

// one step, part 2: combine SPLIT partials, node update, in-place p overwrite
__global__ void combine_kernel(const float* __restrict__ pacc, __half* __restrict__ p,
                               float* __restrict__ prod, const float* __restrict__ prior,
                               float* __restrict__ out, int n, int final_step){
    int i = blockIdx.x*blockDim.x + threadIdx.x;
    if(i < n){
        int b = i >> RSH, k = i & (RSZ-1);
        float a = 0.0f;
        #pragma unroll
        for(int q=0;q<SPLIT;q++)
            a += pacc[(size_t)(b*SPLIT + q)*RSZ + k];
        float pr_old = prod[i];
        float np = pr_old * (1.0f - expf(-a));
        float pr = pr_old * (1.0f - np);
        prod[i] = pr;
        p[i] = __float2half_rn(np);
        if(final_step) out[i] = 1.0f - pr + prior[i];
    }
}

// ---------------- fallback (round-1) kernels ----------------

__global__ void init_kernel(const float* __restrict__ prior, float* __restrict__ p,
                            float* __restrict__ prod, float* __restrict__ agg, int n){
    int i = blockIdx.x*blockDim.x + threadIdx.x;
    if(i<n){ p[i]=prior[i]; prod[i]=1.0f; agg[i]=0.0f; }
}

__global__ void edge_kernel(const int* __restrict__ src, const int* __restrict__ dst,
                            const float* __restrict__ ep, const float* __restrict__ p,
                            float* __restrict__ agg, int e4, int e_rem, long long e4base){
    int i = blockIdx.x*blockDim.x + threadIdx.x;
    if(i < e4){
        int4   s = ((const int4*)src)[i];
        int4   t = ((const int4*)dst)[i];
        float4 w = ((const float4*)ep)[i];
        atomicAdd(&agg[t.x], w.x * p[s.x]);
        atomicAdd(&agg[t.y], w.y * p[s.y]);
        atomicAdd(&agg[t.z], w.z * p[s.z]);
        atomicAdd(&agg[t.w], w.w * p[s.w]);
    }
    if(blockIdx.x==0 && threadIdx.x < e_rem){
        long long e = e4base + threadIdx.x;
        atomicAdd(&agg[dst[e]], ep[e]*p[src[e]]);
    }
}

__global__ void node_kernel(float* __restrict__ p, float* __restrict__ prod,
                            float* __restrict__ agg, const float* __restrict__ prior,
                            float* __restrict__ out, int n, int final_step){
    int i = blockIdx.x*blockDim.x + threadIdx.x;
    if(i<n){
        float a = agg[i]; agg[i]=0.0f;
        float pr_old = prod[i];
        float np = pr_old*(1.0f - expf(-a));
        float pr = pr_old*(1.0f - np);
        prod[i]=pr; p[i]=np;
        if(final_step) out[i] = 1.0f - pr + prior[i];
    }
}

// ---------------- launch ----------------

extern "C" void kernel_launch(void* const* d_in, const int* in_sizes, int n_in,
                              void* d_out, int out_size, void* d_ws, size_t ws_size,
                              hipStream_t stream){
    const float* prior = (const float*)d_in[0];
    const int*   eidx  = (const int*)d_in[1];
    const float* ep    = (const float*)d_in[2];

    const int n = in_sizes[0];
    const long long E = (long long)in_sizes[2];
    const int* src = eidx;
    const int* dst = eidx + E;
    float* out = (float*)d_out;

    const int B = (n + RSZ - 1) >> RSH;   // buckets (489 for n=500000)

    // ws layout
    size_t szNh  = align256((size_t)n * 2);              // fp16 p table
    size_t szN   = align256((size_t)n * 4);              // f32 prod
    size_t szB1  = align256((size_t)(B + 1) * 4);
    size_t szB   = align256((size_t)B * 4);
    size_t szCnt = align256((size_t)SB * B * 4);
    size_t szAcc = align256((size_t)SPLIT * B * RSZ * 4);
    size_t szE2  = align256((size_t)E * 8);

    size_t off_p    = 0;
    size_t off_prod = off_p + szNh;
    size_t off_base = off_prod + szN;
    size_t off_tot  = off_base + szB1;
    size_t off_cnt  = off_tot + szB;
    size_t off_acc  = off_cnt + szCnt;
    size_t off_edge = off_acc + szAcc;
    size_t need     = off_edge + szE2;

    char* ws = (char*)d_ws;

    if(ws_size >= need && n < (1 << SRC_BITS) && B <= NBMAX){
        __half* p    = (__half*)(ws + off_p);
        float*  prod = (float*) (ws + off_prod);
        u32*    base = (u32*)   (ws + off_base);
        u32*    tot  = (u32*)   (ws + off_tot);
        u32*    cnt  = (u32*)   (ws + off_cnt);
        float*  pacc = (float*) (ws + off_acc);
        uint2*  edges= (uint2*) (ws + off_edge);

        const int nb_n = (n + 255)/256;
        init_fast<<<nb_n, 256, 0, stream>>>(prior, p, prod, n);
        hist_kernel<<<SB, HT, (size_t)B*4, stream>>>(dst, E, B, cnt);
        colscan_kernel<<<B, SB, 0, stream>>>(cnt, B, tot);
        basescan_kernel<<<1, 256, 0, stream>>>(tot, base, B);
        scatter_kernel<<<SB, ST, 0, stream>>>(src, dst, ep, E, B, cnt, base, edges);

        for(int step=0; step<NUM_STEPS; ++step){
            step_kernel<<<B*SPLIT, 256, 0, stream>>>(edges, base, p, pacc);
            combine_kernel<<<nb_n, 256, 0, stream>>>(pacc, p, prod, prior, out, n,
                                                     step == NUM_STEPS-1 ? 1 : 0);
        }
    } else {
        // fallback: global-atomic version (round 1)
        float* p    = (float*)d_ws;
        float* prod = p + n;
        float* agg  = prod + n;
        const int nb_n = (n + 255)/256;
        init_kernel<<<nb_n, 256, 0, stream>>>(prior, p, prod, agg, n);
        const int e4 = (int)(E/4);
        const int e_rem = (int)(E%4);
        const long long e4base = (long long)e4*4;
        const int nb_e = (e4 + 255)/256;
        for(int step=0; step<NUM_STEPS; ++step){
            edge_kernel<<<nb_e, 256, 0, stream>>>(src, dst, ep, p, agg, e4, e_rem, e4base);
            node_kernel<<<nb_n, 256, 0, stream>>>(p, prod, agg, prior, out, n,
                                                  step == NUM_STEPS-1 ? 1 : 0);
        }
    }
}